// Round 6
// baseline (684.988 us; speedup 1.0000x reference)
//
#include <hip/hip_runtime.h>
#include <math.h>

#define NS 56        // B*(T-1)
#define NPIX 65536   // 256*256
#define NB_RED 1024

static constexpr double D_PI = 3.14159265358979323846;

typedef __attribute__((ext_vector_type(8))) short short8;
typedef __attribute__((ext_vector_type(4))) float f32x4;

__device__ inline unsigned short f2bf(float f) {
  union { float f; unsigned int u; } v; v.f = f;
  unsigned int r = v.u + 0x7FFFu + ((v.u >> 16) & 1u);
  return (unsigned short)(r >> 16);
}
__device__ inline float bf2f(unsigned short b) {
  union { float f; unsigned int u; } v; v.u = ((unsigned int)b) << 16;
  return v.f;
}

// ---------------- workspace layout (float offsets) ----------------
#define OFF_PART 0                        // 2048 doubles
#define OFF_S    4096                     // 256*256 bf16 = 32768 f
#define OFF_HM   (OFF_S + 32768)          // 65536 f
#define OFF_H    (OFF_HM + 65536)         // 56*65536 f
#define SLC      (NS * NPIX)
#define OFF_Q0   (OFF_H + SLC)
#define OFF_Q1   (OFF_Q0 + SLC)
#define OFF_QB   (OFF_Q1 + SLC)
#define OFF_TA   (OFF_QB + SLC)           // bf16: SLC/2 floats
#define OFF_U    (OFF_TA + SLC / 2)
#define OFF_V    (OFF_U + SLC / 2)
// conv phase reuses QG region (all QG data dead after k_red_dyn)
#define OFF_XP   OFF_H                    // 4*65536*16 bf16 = 2097152 f
#define OFF_Z1   (OFF_XP + 2097152)       // 4*65536*64 bf16 = 8388608 f
#define OFF_Z2   (OFF_Z1 + 8388608)
#define OFF_BC   (OFF_Z2 + 8388608)
#define OFF_XA   (OFF_BC + 8388608)       // 4*65536*16 bf16 = 2097152 f
#define OFF_WT   (OFF_XA + 2097152)
// weight regions in SHORT offsets from wtb
#define W_IN    0                         // 5*4*64*8   = 10240
#define W_HID   10240                     // 2 halves x 18432
#define W_B1    47104
#define W_B21   83968
#define W_B22   120832
#define W_O1    157696                    // 18*4*16*8 = 9216
#define W_O2    166912                    // contiguous with O1

#define QCLAMP 1.0e12f
#define HCLAMP 1.0e15f

// ---------------- init: DST matrix (bf16) + Helmholtz eigenvalues ----------------
__global__ __launch_bounds__(256) void k_dst_init(unsigned short* __restrict__ S,
                                                  float* __restrict__ HM, float dx2f) {
  int idx = blockIdx.x * 256 + threadIdx.x;
  int i = idx >> 8, j = idx & 255;
  float sv = 0.f, hv = 1.f;
  if (i < 254 && j < 254) {
    double arg = D_PI * (double)((i + 1) * (j + 1)) / 255.0;
    sv = (float)((2.0 / sqrt(510.0)) * sin(arg));
    double la = 2.0 * (cos(D_PI * (double)(i + 1) / 255.0) - 1.0) / (double)dx2f
              + 2.0 * (cos(D_PI * (double)(j + 1) / 255.0) - 1.0) / (double)dx2f;
    hv = (float)((9.81 / 1e-4) * la - 9.81 * 1e-4 / (2.7 * 2.7));
  }
  S[idx] = f2bf(sv);
  HM[idx] = hv;
}

// ---------------- QG init ----------------
__global__ __launch_bounds__(256) void k_qg_init(const float* __restrict__ x,
                                                 float* __restrict__ h,
                                                 float* __restrict__ q,
                                                 float* __restrict__ qb,
                                                 float dx2, float gf, float gfc) {
  int idx = blockIdx.x * 256 + threadIdx.x;
  int s = idx >> 16, p = idx & 65535;
  int y = p >> 8, xx = p & 255;
  int b = s / 14, t = s - b * 14;
  const float* hb = x + (size_t)(b * 15 + t) * NPIX;
  float hc = hb[p];
  float qv;
  if (y >= 2 && y <= 252 && xx >= 2 && xx <= 252) {
    qv = gf * ((hb[p + 256] + hb[p - 256] - 2.f * hc) / dx2
             + (hb[p + 1] + hb[p - 1] - 2.f * hc) / dx2) - gfc * hc;
  } else {
    qv = -gfc * hc;
  }
  h[idx] = hc;
  q[idx] = qv;
  qb[idx] = qv;
}

// ---------------- q1 update + padded bf16 qin ----------------
__global__ __launch_bounds__(256) void k_qrhs(const float* __restrict__ h,
                                              const float* __restrict__ qc,
                                              const float* __restrict__ qb,
                                              float* __restrict__ qn,
                                              unsigned short* __restrict__ tA,
                                              float ngf, float pgf, float fdx,
                                              float cc, float dtf) {
  int idx = blockIdx.x * 256 + threadIdx.x;
  int s = idx >> 16, p = idx & 65535;
  int y = p >> 8, xx = p & 255;
  const float* H = h + (size_t)s * NPIX;
  const float* Q = qc + (size_t)s * NPIX;
  float qv = Q[p];
  float q1 = qv;
  if (y >= 2 && y <= 252 && xx >= 2 && xx <= 252) {
    float hSW = H[p + 255], hS = H[p + 256], hSE = H[p + 257];
    float hNW = H[p - 257], hN = H[p - 256], hNE = H[p - 255];
    float hW = H[p - 1], hE = H[p + 1];
    float uA = ngf * (hSW + hS - hN - hNW) / fdx;
    float uB = ngf * (hS + hSE - hNE - hN) / fdx;
    float vA = pgf * (hE + hNE - hNW - hW) / fdx;
    float vB = pgf * (hSE + hE - hW - hSW) / fdx;
    float uT = 0.5f * (uA + uB);
    float vT = 0.5f * (vA + vB);
    float up = fmaxf(uT, 0.f), um = fminf(uT, 0.f);
    float vp = fmaxf(vT, 0.f), vm = fminf(vT, 0.f);
    float Q0 = qv;
    float QE = Q[p + 1], QW = Q[p - 1], QEE = Q[p + 2], QWW = Q[p - 2];
    float QS = Q[p + 256], QN = Q[p - 256], QSS = Q[p + 512], QNN = Q[p - 512];
    float r = -up * cc * (2.f * QE + 3.f * Q0 - 6.f * QW + QWW)
            + um * cc * (QEE - 6.f * QE + 3.f * Q0 + 2.f * QW)
            - vp * cc * (2.f * QS + 3.f * Q0 - 6.f * QN + QNN)
            + vm * cc * (QSS - 6.f * QS + 3.f * Q0 + 2.f * QN);
    q1 = qv + dtf * r;
    q1 = fminf(fmaxf(q1, -QCLAMP), QCLAMP);
  }
  qn[idx] = q1;
  int wy = (y == 0) ? 254 : ((y == 255) ? 255 : y - 1);
  int wx = (xx == 0) ? 254 : ((xx == 255) ? 255 : xx - 1);
  float val = 0.f;
  if (y >= 1 && y <= 254 && xx >= 1 && xx <= 254) val = q1 - qb[idx];
  tA[(size_t)s * NPIX + wy * 256 + wx] = f2bf(val);
}

// ---------------- MFMA GEMM: C = S @ X^T (256x256, S symmetric bf16) ----------------
template <int EPI>
__global__ __launch_bounds__(256) void k_gemm_mfma(const unsigned short* __restrict__ Sm,
                                                   const unsigned short* __restrict__ Xb,
                                                   unsigned short* __restrict__ Cb,
                                                   const float* __restrict__ HM,
                                                   const float* __restrict__ xin,
                                                   float* __restrict__ hout) {
  int s = blockIdx.z;
  const unsigned short* X = Xb + (size_t)s * NPIX;
  int lane = threadIdx.x & 63, wave = threadIdx.x >> 6;
  int cl = lane & 15, kg = lane >> 4;
  int m0 = blockIdx.y * 64 + (wave >> 1) * 32;
  int n0 = blockIdx.x * 64 + (wave & 1) * 32;
  f32x4 acc[2][2];
#pragma unroll
  for (int i = 0; i < 2; ++i)
#pragma unroll
    for (int j = 0; j < 2; ++j) acc[i][j] = (f32x4){0.f, 0.f, 0.f, 0.f};
#pragma unroll
  for (int kc = 0; kc < 256; kc += 32) {
    short8 a[2], b[2];
#pragma unroll
    for (int t = 0; t < 2; ++t) {
      a[t] = *(const short8*)&Sm[(size_t)(m0 + t * 16 + cl) * 256 + kc + kg * 8];
      b[t] = *(const short8*)&X[(size_t)(n0 + t * 16 + cl) * 256 + kc + kg * 8];
    }
#pragma unroll
    for (int i = 0; i < 2; ++i)
#pragma unroll
      for (int j = 0; j < 2; ++j)
        acc[i][j] = __builtin_amdgcn_mfma_f32_16x16x32_bf16(a[i], b[j], acc[i][j], 0, 0, 0);
  }
  if (EPI == 0 || EPI == 1) {
    unsigned short* C = Cb + (size_t)s * NPIX;
#pragma unroll
    for (int i = 0; i < 2; ++i)
#pragma unroll
      for (int j = 0; j < 2; ++j)
#pragma unroll
        for (int r = 0; r < 4; ++r) {
          int gm = m0 + i * 16 + kg * 4 + r;
          int gn = n0 + j * 16 + cl;
          float v = acc[i][j][r];
          if (EPI == 1) v /= HM[(size_t)gm * 256 + gn];
          C[(size_t)gm * 256 + gn] = f2bf(v);
        }
  } else {
    int b = s / 14, t = s - b * 14;
    const float* hb = xin + (size_t)(b * 15 + t) * NPIX;
    float* H = hout + (size_t)s * NPIX;
#pragma unroll
    for (int i = 0; i < 2; ++i)
#pragma unroll
      for (int j = 0; j < 2; ++j)
#pragma unroll
        for (int r = 0; r < 4; ++r) {
          int gm = m0 + i * 16 + kg * 4 + r;
          int gn = n0 + j * 16 + cl;
          if (gm < 254 && gn < 254) {
            size_t o = (size_t)(gm + 1) * 256 + (gn + 1);
            float hv = acc[i][j][r] + hb[o];
            H[o] = fminf(fmaxf(hv, -HCLAMP), HCLAMP);
          }
        }
  }
}

// ---------------- pack x -> NHWC(16) bf16 ----------------
__global__ __launch_bounds__(256) void k_pack_x(const float* __restrict__ x,
                                                unsigned short* __restrict__ xp) {
  int e = blockIdx.x * 256 + threadIdx.x;
  int b = e >> 16, p = e & 65535;
  const float* xb = x + (size_t)b * 15 * NPIX + p;
  union { unsigned short u16[16]; uint4 u4[2]; } vv;
#pragma unroll
  for (int c = 0; c < 15; ++c) vv.u16[c] = f2bf(xb[(size_t)c * NPIX]);
  vv.u16[15] = 0;
  uint4* dst = (uint4*)&xp[(size_t)e * 16];
  dst[0] = vv.u4[0];
  dst[1] = vv.u4[1];
}

// ---------------- weight prep: OIHW f32 -> [chunk][kg][ocw][8] bf16 ----------------
__global__ __launch_bounds__(256) void k_wprep(const float* __restrict__ src,
                                               unsigned short* __restrict__ dst,
                                               int chunks, int icpShift, int icw, int ic0,
                                               int icReal, int ocw, int oc0, int ocReal) {
  int e = blockIdx.x * 256 + threadIdx.x;
  int total = chunks * 4 * ocw * 8;
  if (e >= total) return;
  int j = e & 7;
  int oc = (e >> 3) % ocw;
  int ckg = e / (8 * ocw);
  int kg = ckg & 3, c = ckg >> 2;
  int Kidx = c * 32 + kg * 8 + j;
  int tap = Kidx >> icpShift;
  int ic = Kidx & ((1 << icpShift) - 1);
  float v = 0.f;
  if (tap < 9 && ic < icReal && (oc0 + oc) < ocReal)
    v = src[((size_t)(oc0 + oc) * icw + ic0 + ic) * 9 + tap];
  dst[e] = f2bf(v);
}

// ---------------- MFMA 3x3 conv, 64-ch input, all-LDS operands ----------------
// Block: 16x16 px, 4 waves x 4 rows, OCW=NOC*16 out channels (oc-split via z).
// Weights (this block's oc slice, all NSRC sources) staged once in LDS;
// input tile staged per (src, ch-half) as 18x18x32ch with XOR swizzle
// g' = g ^ ((pp>>1)&3) -> 2 lanes/bank (free). Inner loop: pure ds_read+MFMA.
template <int NOC, int NSRC, int OCF, bool RELU, int EMODE>
__global__ __launch_bounds__(256) void k_conv64(const unsigned short* __restrict__ in0,
                                                const unsigned short* __restrict__ in1,
                                                const unsigned short* __restrict__ wt,
                                                const float* __restrict__ bias, int ocReal,
                                                const unsigned short* __restrict__ other,
                                                unsigned short* __restrict__ out) {
  constexpr int OCW = NOC * 16;
  constexpr int WSH = NSRC * 18 * 4 * OCW * 8;   // shorts of weights in LDS
  __shared__ unsigned short wlds[WSH];
  __shared__ unsigned short tile[324 * 32];

  const int tid = threadIdx.x;
  const int lane = tid & 63, wave = tid >> 6;
  const int cl = lane & 15, kg = lane >> 4;
  int zb = blockIdx.z;
  int b, ocBase;
  if (NOC == 2) { b = zb & 3; ocBase = (zb >> 2) * 32; }
  else          { b = zb;     ocBase = 0; }
  const int gx0 = blockIdx.x * 16, gy0 = blockIdx.y * 16;

  // ---- stage weights (this oc-slice) ----
  {
    const unsigned short* wtp = (NOC == 2) ? wt + (size_t)(zb >> 2) * WSH : wt;
    uint4* wl = (uint4*)wlds;
    const uint4* wg = (const uint4*)wtp;
    for (int i = tid; i < WSH / 8; i += 256) wl[i] = wg[i];
  }

  f32x4 acc[4][NOC];
#pragma unroll
  for (int j = 0; j < NOC; ++j) {
    int oc = ocBase + j * 16 + cl;
    float bv = (bias != nullptr && oc < ocReal) ? bias[oc] : 0.f;
#pragma unroll
    for (int i = 0; i < 4; ++i) acc[i][j] = (f32x4){bv, bv, bv, bv};
  }

  for (int src = 0; src < NSRC; ++src) {
    const unsigned short* inb = (src ? in1 : in0) + (size_t)b * NPIX * 64;
    for (int h = 0; h < 2; ++h) {
      if (src || h) __syncthreads();        // previous compute done
      // ---- stage 18x18 x 32ch tile (zero halo, swizzled) ----
      for (int c = tid; c < 1296; c += 256) {
        int pp = c >> 2, g = c & 3;
        int ly = pp / 18, lx = pp - ly * 18;
        int iy = gy0 + ly - 1, ix = gx0 + lx - 1;
        uint4 v = make_uint4(0u, 0u, 0u, 0u);
        if (iy >= 0 && iy < 256 && ix >= 0 && ix < 256)
          v = *(const uint4*)&inb[((size_t)iy * 256 + ix) * 64 + h * 32 + g * 8];
        int sw = g ^ ((pp >> 1) & 3);
        *(uint4*)&tile[pp * 32 + sw * 8] = v;
      }
      __syncthreads();                      // weights (1st iter) + tile ready
      // ---- compute 9 chunks ----
#pragma unroll
      for (int c9 = 0; c9 < 9; ++c9) {
        const int cm = src * 18 + 2 * c9 + h;
        const int dy = c9 / 3, dxx = c9 - dy * 3;
        short8 bfr[NOC];
#pragma unroll
        for (int j = 0; j < NOC; ++j)
          bfr[j] = *(const short8*)&wlds[((cm * 4 + kg) * OCW + j * 16 + cl) * 8];
        const int tc = cl + dxx;
#pragma unroll
        for (int i = 0; i < 4; ++i) {
          int pp = (wave * 4 + i + dy) * 18 + tc;
          int g2 = kg ^ ((pp >> 1) & 3);
          short8 av = *(const short8*)&tile[pp * 32 + g2 * 8];
#pragma unroll
          for (int j = 0; j < NOC; ++j)
            acc[i][j] = __builtin_amdgcn_mfma_f32_16x16x32_bf16(av, bfr[j], acc[i][j], 0, 0, 0);
        }
      }
    }
  }

  const size_t outBase = (size_t)b * NPIX * OCF;
#pragma unroll
  for (int i = 0; i < 4; ++i) {
    int y = gy0 + wave * 4 + i;
#pragma unroll
    for (int j = 0; j < NOC; ++j) {
      int oc = ocBase + j * 16 + cl;
#pragma unroll
      for (int r = 0; r < 4; ++r) {
        int px = gx0 + kg * 4 + r;
        size_t oi = outBase + ((size_t)y * 256 + px) * OCF + oc;
        float v = acc[i][j][r];
        if (EMODE == 1) v *= bf2f(other[oi]);
        if (RELU) v = fmaxf(v, 0.f);
        out[oi] = f2bf(v);
      }
    }
  }
}

// ---------------- MFMA 3x3 conv, 16-ch input (conv_in), all-LDS ----------------
__global__ __launch_bounds__(256) void k_conv16(const unsigned short* __restrict__ in,
                                                const unsigned short* __restrict__ wt,
                                                const float* __restrict__ bias,
                                                unsigned short* __restrict__ out) {
  __shared__ unsigned short wlds[10240];     // 5 chunks x 4 x 64 x 8
  __shared__ unsigned short tile[324 * 16];

  const int tid = threadIdx.x;
  const int lane = tid & 63, wave = tid >> 6;
  const int cl = lane & 15, kg = lane >> 4;
  const int b = blockIdx.z;
  const int gx0 = blockIdx.x * 16, gy0 = blockIdx.y * 16;

  {
    uint4* wl = (uint4*)wlds;
    const uint4* wg = (const uint4*)wt;
    for (int i = tid; i < 1280; i += 256) wl[i] = wg[i];
  }
  const unsigned short* inb = in + (size_t)b * NPIX * 16;
  for (int c = tid; c < 648; c += 256) {
    int pp = c >> 1, g = c & 1;
    int ly = pp / 18, lx = pp - ly * 18;
    int iy = gy0 + ly - 1, ix = gx0 + lx - 1;
    uint4 v = make_uint4(0u, 0u, 0u, 0u);
    if (iy >= 0 && iy < 256 && ix >= 0 && ix < 256)
      v = *(const uint4*)&inb[((size_t)iy * 256 + ix) * 16 + g * 8];
    int sw = g ^ (pp & 1);
    *(uint4*)&tile[pp * 16 + sw * 8] = v;
  }
  __syncthreads();

  f32x4 acc[4][4];
#pragma unroll
  for (int j = 0; j < 4; ++j) {
    float bv = bias[j * 16 + cl];
#pragma unroll
    for (int i = 0; i < 4; ++i) acc[i][j] = (f32x4){bv, bv, bv, bv};
  }

#pragma unroll
  for (int c = 0; c < 5; ++c) {
    int tap = 2 * c + (kg >> 1);             // tap 9: zero weights
    int dy = tap / 3, dxx = tap - dy * 3;
    int gidx = kg & 1;
    short8 bfr[4];
#pragma unroll
    for (int j = 0; j < 4; ++j)
      bfr[j] = *(const short8*)&wlds[((c * 4 + kg) * 64 + j * 16 + cl) * 8];
    int tc = cl + dxx;
#pragma unroll
    for (int i = 0; i < 4; ++i) {
      int tr = wave * 4 + i + dy;
      if (tr > 17) tr = 17;                  // tap 9 only
      int pp = tr * 18 + tc;
      int g2 = gidx ^ (pp & 1);
      short8 av = *(const short8*)&tile[pp * 16 + g2 * 8];
#pragma unroll
      for (int j = 0; j < 4; ++j)
        acc[i][j] = __builtin_amdgcn_mfma_f32_16x16x32_bf16(av, bfr[j], acc[i][j], 0, 0, 0);
    }
  }

  const size_t outBase = (size_t)b * NPIX * 64;
#pragma unroll
  for (int i = 0; i < 4; ++i) {
    int y = gy0 + wave * 4 + i;
#pragma unroll
    for (int j = 0; j < 4; ++j) {
      int oc = j * 16 + cl;
#pragma unroll
      for (int r = 0; r < 4; ++r) {
        int px = gx0 + kg * 4 + r;
        size_t oi = outBase + ((size_t)y * 256 + px) * 64 + oc;
        out[oi] = f2bf(fmaxf(acc[i][j][r], 0.f));   // relu on store
      }
    }
  }
}

// ---------------- reductions ----------------
__global__ __launch_bounds__(256) void k_red_dyn(const float* __restrict__ x,
                                                 const float* __restrict__ h,
                                                 double* __restrict__ part) {
  double sum = 0.0;
  for (int e = blockIdx.x * 256 + threadIdx.x; e < NS * NPIX; e += NB_RED * 256) {
    int s = e >> 16, p = e & 65535;
    int b = s / 14, t = s - b * 14;
    float d = x[(size_t)(b * 15 + t + 1) * NPIX + p] - h[e];
    sum += (double)d * (double)d;
  }
  for (int o = 32; o > 0; o >>= 1) sum += __shfl_down(sum, o);
  __shared__ double sw[4];
  int lane = threadIdx.x & 63, wid = threadIdx.x >> 6;
  if (lane == 0) sw[wid] = sum;
  __syncthreads();
  if (threadIdx.x == 0) part[blockIdx.x] = sw[0] + sw[1] + sw[2] + sw[3];
}

__global__ __launch_bounds__(256) void k_red_ae(const float* __restrict__ x,
                                                const unsigned short* __restrict__ xa,
                                                double* __restrict__ part) {
  double sum = 0.0;
  for (int e = blockIdx.x * 256 + threadIdx.x; e < 60 * NPIX; e += NB_RED * 256) {
    int b = e / (15 * NPIX);
    int r2 = e - b * 15 * NPIX;
    int c = r2 >> 16, p = r2 & 65535;
    float xav = bf2f(xa[((size_t)b * NPIX + p) * 16 + c]);
    float d = x[e] - xav;
    sum += (double)d * (double)d;
  }
  for (int o = 32; o > 0; o >>= 1) sum += __shfl_down(sum, o);
  __shared__ double sw[4];
  int lane = threadIdx.x & 63, wid = threadIdx.x >> 6;
  if (lane == 0) sw[wid] = sum;
  __syncthreads();
  if (threadIdx.x == 0) part[NB_RED + blockIdx.x] = sw[0] + sw[1] + sw[2] + sw[3];
}

__global__ __launch_bounds__(256) void k_final(const double* __restrict__ part,
                                               float* __restrict__ out) {
  double s1 = 0.0, s2 = 0.0;
  for (int i = threadIdx.x; i < NB_RED; i += 256) {
    s1 += part[i];
    s2 += part[NB_RED + i];
  }
  for (int o = 32; o > 0; o >>= 1) {
    s1 += __shfl_down(s1, o);
    s2 += __shfl_down(s2, o);
  }
  __shared__ double a1[4], a2[4];
  int lane = threadIdx.x & 63, wid = threadIdx.x >> 6;
  if (lane == 0) { a1[wid] = s1; a2[wid] = s2; }
  __syncthreads();
  if (threadIdx.x == 0) {
    double v = (a1[0] + a1[1] + a1[2] + a1[3]) / (double)(NS * NPIX)
             + (a2[0] + a2[1] + a2[2] + a2[3]) / (double)(60 * NPIX);
    if (!(v == v)) v = 0.0;
    if (v > 1.0e30) v = 1.0e30;
    if (v < -1.0e30) v = -1.0e30;
    out[0] = (float)v;
  }
}

// ---------------- launcher ----------------
extern "C" void kernel_launch(void* const* d_in, const int* in_sizes, int n_in,
                              void* d_out, int out_size, void* d_ws, size_t ws_size,
                              hipStream_t stream) {
  (void)in_sizes; (void)n_in; (void)out_size; (void)ws_size;
  const float* x     = (const float*)d_in[0];
  const float* w_in  = (const float*)d_in[1];
  const float* b_in  = (const float*)d_in[2];
  const float* w_hid = (const float*)d_in[3];
  const float* b_hid = (const float*)d_in[4];
  const float* w_b1  = (const float*)d_in[5];
  const float* b_b1  = (const float*)d_in[6];
  const float* w_b21 = (const float*)d_in[7];
  const float* b_b21 = (const float*)d_in[8];
  const float* w_b22 = (const float*)d_in[9];
  const float* b_b22 = (const float*)d_in[10];
  const float* w_out = (const float*)d_in[11];
  const float* b_out = (const float*)d_in[12];
  float* ws = (float*)d_ws;
  float* out = (float*)d_out;

  double mc = 0.0;
  for (int k = 0; k < 256; ++k) mc += cos((32.0 + 0.05 * k) * D_PI / 180.0);
  mc /= 256.0;
  float DXf = (float)(0.5 * (5550.0 + 5550.0 * mc));
  float dx2 = DXf * DXf;
  float gf  = (float)(9.81 / 1e-4);
  float ngf = (float)(-9.81 / 1e-4);
  float gfc = (float)(9.81 * 1e-4 / (2.7 * 2.7));
  float fdx = 4.0f * DXf;
  float cc  = 1.0f / (6.0f * DXf);
  float dtf = 21600.0f;

  double* part = (double*)d_ws;
  unsigned short* S  = (unsigned short*)(ws + OFF_S);
  float* HM = ws + OFF_HM;
  float* h  = ws + OFF_H;
  float* q0 = ws + OFF_Q0;
  float* q1 = ws + OFF_Q1;
  float* qb = ws + OFF_QB;
  unsigned short* tA = (unsigned short*)(ws + OFF_TA);
  unsigned short* U  = (unsigned short*)(ws + OFF_U);
  unsigned short* V  = (unsigned short*)(ws + OFF_V);
  unsigned short* wtb = (unsigned short*)(ws + OFF_WT);

  k_dst_init<<<dim3(256), dim3(256), 0, stream>>>(S, HM, dx2);

  // weight prep: (src, dst, chunks, icpShift, icw, ic0, icReal, ocw, oc0, ocReal)
  k_wprep<<<dim3(40), dim3(256), 0, stream>>>(w_in, wtb + W_IN, 5, 4, 15, 0, 15, 64, 0, 64);
  const float* wsrc[4] = {w_hid, w_b1, w_b21, w_b22};
  const int wdst[4] = {W_HID, W_B1, W_B21, W_B22};
  for (int cv = 0; cv < 4; ++cv)
    for (int hf = 0; hf < 2; ++hf)
      k_wprep<<<dim3(72), dim3(256), 0, stream>>>(wsrc[cv], wtb + wdst[cv] + hf * 18432,
                                                  18, 6, 64, 0, 64, 32, hf * 32, 64);
  k_wprep<<<dim3(36), dim3(256), 0, stream>>>(w_out, wtb + W_O1, 18, 6, 128, 0, 64, 16, 0, 15);
  k_wprep<<<dim3(36), dim3(256), 0, stream>>>(w_out, wtb + W_O2, 18, 6, 128, 64, 64, 16, 0, 15);

  k_qg_init<<<dim3(NS * NPIX / 256), dim3(256), 0, stream>>>(x, h, q0, qb, dx2, gf, gfc);

  float* qc = q0;
  float* qn = q1;
  dim3 gg(4, 4, NS);
  for (int step = 0; step < 4; ++step) {
    k_qrhs<<<dim3(NS * NPIX / 256), dim3(256), 0, stream>>>(h, qc, qb, qn, tA,
                                                            ngf, gf, fdx, cc, dtf);
    k_gemm_mfma<0><<<gg, dim3(256), 0, stream>>>(S, tA, U, nullptr, nullptr, nullptr);
    k_gemm_mfma<1><<<gg, dim3(256), 0, stream>>>(S, U, V, HM, nullptr, nullptr);
    k_gemm_mfma<0><<<gg, dim3(256), 0, stream>>>(S, V, U, nullptr, nullptr, nullptr);
    k_gemm_mfma<2><<<gg, dim3(256), 0, stream>>>(S, U, nullptr, nullptr, x, h);
    float* tmp = qc; qc = qn; qn = tmp;
  }
  k_red_dyn<<<dim3(NB_RED), dim3(256), 0, stream>>>(x, h, part);

  unsigned short* xp = (unsigned short*)(ws + OFF_XP);
  unsigned short* z1 = (unsigned short*)(ws + OFF_Z1);
  unsigned short* z2 = (unsigned short*)(ws + OFF_Z2);
  unsigned short* bc = (unsigned short*)(ws + OFF_BC);
  unsigned short* xa = (unsigned short*)(ws + OFF_XA);

  k_pack_x<<<dim3(4 * NPIX / 256), dim3(256), 0, stream>>>(x, xp);

  dim3 cg4(16, 16, 4);
  dim3 cg8(16, 16, 8);
  // conv_in: xp(16) -> z1 (relu on store)
  k_conv16<<<cg4, dim3(256), 0, stream>>>(xp, wtb + W_IN, b_in, z1);
  // hid: z1 -> z2
  k_conv64<2, 1, 64, false, 0><<<cg8, dim3(256), 0, stream>>>(
      z1, z1, wtb + W_HID, b_hid, 64, nullptr, z2);
  // b1: z2 -> z1
  k_conv64<2, 1, 64, false, 0><<<cg8, dim3(256), 0, stream>>>(
      z2, z2, wtb + W_B1, b_b1, 64, nullptr, z1);
  // b21: z2 -> bc
  k_conv64<2, 1, 64, false, 0><<<cg8, dim3(256), 0, stream>>>(
      z2, z2, wtb + W_B21, b_b21, 64, nullptr, bc);
  // b22: z2 -> bc (multiply by other=bc)
  k_conv64<2, 1, 64, false, 1><<<cg8, dim3(256), 0, stream>>>(
      z2, z2, wtb + W_B22, b_b22, 64, bc, bc);
  // out: concat(z1, bc) -> xa (dual source, 16 oc)
  k_conv64<1, 2, 16, false, 0><<<cg4, dim3(256), 0, stream>>>(
      z1, bc, wtb + W_O1, b_out, 15, nullptr, xa);

  k_red_ae<<<dim3(NB_RED), dim3(256), 0, stream>>>(x, xa, part);
  k_final<<<dim3(1), dim3(256), 0, stream>>>(part, out);
}

// Round 7
// 625.144 us; speedup vs baseline: 1.0957x; 1.0957x over previous
//
#include <hip/hip_runtime.h>
#include <math.h>

#define NS 56        // B*(T-1)
#define NPIX 65536   // 256*256
#define NB_RED 1024

static constexpr double D_PI = 3.14159265358979323846;

typedef __attribute__((ext_vector_type(8))) short short8;
typedef __attribute__((ext_vector_type(4))) float f32x4;
typedef __attribute__((ext_vector_type(16))) float f32x16;

__device__ inline unsigned short f2bf(float f) {
  union { float f; unsigned int u; } v; v.f = f;
  unsigned int r = v.u + 0x7FFFu + ((v.u >> 16) & 1u);
  return (unsigned short)(r >> 16);
}
__device__ inline float bf2f(unsigned short b) {
  union { float f; unsigned int u; } v; v.u = ((unsigned int)b) << 16;
  return v.f;
}

// ---------------- workspace layout (float offsets) ----------------
#define OFF_PART 0                        // 2048 doubles
#define OFF_S    4096
#define OFF_HM   (OFF_S + 32768)
#define OFF_H    (OFF_HM + 65536)
#define SLC      (NS * NPIX)
#define OFF_Q0   (OFF_H + SLC)
#define OFF_Q1   (OFF_Q0 + SLC)
#define OFF_QB   (OFF_Q1 + SLC)
#define OFF_TA   (OFF_QB + SLC)
#define OFF_U    (OFF_TA + SLC / 2)
#define OFF_V    (OFF_U + SLC / 2)
// conv phase reuses QG region
#define OFF_XP   OFF_H
#define OFF_Z1   (OFF_XP + 2097152)
#define OFF_Z2   (OFF_Z1 + 8388608)
#define OFF_BC   (OFF_Z2 + 8388608)
#define OFF_XA   (OFF_BC + 8388608)
#define OFF_WT   (OFF_XA + 2097152)
// weight regions in SHORT offsets from wtb (full 64-oc layouts)
#define W_IN    0                         // 5*4*64*8   = 10240
#define W_HID   10240                     // 18*4*64*8  = 36864
#define W_B1    47104
#define W_B21   83968
#define W_B22   120832
#define W_O1    157696                    // 18*4*16*8  = 9216
#define W_O2    166912

#define QCLAMP 1.0e12f
#define HCLAMP 1.0e15f

// ---------------- init: DST matrix (bf16) + Helmholtz eigenvalues ----------------
__global__ __launch_bounds__(256) void k_dst_init(unsigned short* __restrict__ S,
                                                  float* __restrict__ HM, float dx2f) {
  int idx = blockIdx.x * 256 + threadIdx.x;
  int i = idx >> 8, j = idx & 255;
  float sv = 0.f, hv = 1.f;
  if (i < 254 && j < 254) {
    double arg = D_PI * (double)((i + 1) * (j + 1)) / 255.0;
    sv = (float)((2.0 / sqrt(510.0)) * sin(arg));
    double la = 2.0 * (cos(D_PI * (double)(i + 1) / 255.0) - 1.0) / (double)dx2f
              + 2.0 * (cos(D_PI * (double)(j + 1) / 255.0) - 1.0) / (double)dx2f;
    hv = (float)((9.81 / 1e-4) * la - 9.81 * 1e-4 / (2.7 * 2.7));
  }
  S[idx] = f2bf(sv);
  HM[idx] = hv;
}

// ---------------- QG init ----------------
__global__ __launch_bounds__(256) void k_qg_init(const float* __restrict__ x,
                                                 float* __restrict__ h,
                                                 float* __restrict__ q,
                                                 float* __restrict__ qb,
                                                 float dx2, float gf, float gfc) {
  int idx = blockIdx.x * 256 + threadIdx.x;
  int s = idx >> 16, p = idx & 65535;
  int y = p >> 8, xx = p & 255;
  int b = s / 14, t = s - b * 14;
  const float* hb = x + (size_t)(b * 15 + t) * NPIX;
  float hc = hb[p];
  float qv;
  if (y >= 2 && y <= 252 && xx >= 2 && xx <= 252) {
    qv = gf * ((hb[p + 256] + hb[p - 256] - 2.f * hc) / dx2
             + (hb[p + 1] + hb[p - 1] - 2.f * hc) / dx2) - gfc * hc;
  } else {
    qv = -gfc * hc;
  }
  h[idx] = hc;
  q[idx] = qv;
  qb[idx] = qv;
}

// ---------------- q1 update + padded bf16 qin ----------------
__global__ __launch_bounds__(256) void k_qrhs(const float* __restrict__ h,
                                              const float* __restrict__ qc,
                                              const float* __restrict__ qb,
                                              float* __restrict__ qn,
                                              unsigned short* __restrict__ tA,
                                              float ngf, float pgf, float fdx,
                                              float cc, float dtf) {
  int idx = blockIdx.x * 256 + threadIdx.x;
  int s = idx >> 16, p = idx & 65535;
  int y = p >> 8, xx = p & 255;
  const float* H = h + (size_t)s * NPIX;
  const float* Q = qc + (size_t)s * NPIX;
  float qv = Q[p];
  float q1 = qv;
  if (y >= 2 && y <= 252 && xx >= 2 && xx <= 252) {
    float hSW = H[p + 255], hS = H[p + 256], hSE = H[p + 257];
    float hNW = H[p - 257], hN = H[p - 256], hNE = H[p - 255];
    float hW = H[p - 1], hE = H[p + 1];
    float uA = ngf * (hSW + hS - hN - hNW) / fdx;
    float uB = ngf * (hS + hSE - hNE - hN) / fdx;
    float vA = pgf * (hE + hNE - hNW - hW) / fdx;
    float vB = pgf * (hSE + hE - hW - hSW) / fdx;
    float uT = 0.5f * (uA + uB);
    float vT = 0.5f * (vA + vB);
    float up = fmaxf(uT, 0.f), um = fminf(uT, 0.f);
    float vp = fmaxf(vT, 0.f), vm = fminf(vT, 0.f);
    float Q0 = qv;
    float QE = Q[p + 1], QW = Q[p - 1], QEE = Q[p + 2], QWW = Q[p - 2];
    float QS = Q[p + 256], QN = Q[p - 256], QSS = Q[p + 512], QNN = Q[p - 512];
    float r = -up * cc * (2.f * QE + 3.f * Q0 - 6.f * QW + QWW)
            + um * cc * (QEE - 6.f * QE + 3.f * Q0 + 2.f * QW)
            - vp * cc * (2.f * QS + 3.f * Q0 - 6.f * QN + QNN)
            + vm * cc * (QSS - 6.f * QS + 3.f * Q0 + 2.f * QN);
    q1 = qv + dtf * r;
    q1 = fminf(fmaxf(q1, -QCLAMP), QCLAMP);
  }
  qn[idx] = q1;
  int wy = (y == 0) ? 254 : ((y == 255) ? 255 : y - 1);
  int wx = (xx == 0) ? 254 : ((xx == 255) ? 255 : xx - 1);
  float val = 0.f;
  if (y >= 1 && y <= 254 && xx >= 1 && xx <= 254) val = q1 - qb[idx];
  tA[(size_t)s * NPIX + wy * 256 + wx] = f2bf(val);
}

// ---------------- MFMA GEMM (32x32x16): C = S @ X^T ----------------
// EPI 0: store C bf16. EPI 1: store (C/HM) bf16. EPI 2: h[int] = clamp(C + hb)
template <int EPI>
__global__ __launch_bounds__(256) void k_gemm_mfma(const unsigned short* __restrict__ Sm,
                                                   const unsigned short* __restrict__ Xb,
                                                   unsigned short* __restrict__ Cb,
                                                   const float* __restrict__ HM,
                                                   const float* __restrict__ xin,
                                                   float* __restrict__ hout) {
  int s = blockIdx.z;
  const unsigned short* X = Xb + (size_t)s * NPIX;
  int lane = threadIdx.x & 63, wave = threadIdx.x >> 6;
  int r31 = lane & 31, kh = lane >> 5;
  int m0 = blockIdx.y * 64 + (wave >> 1) * 32;
  int n0 = blockIdx.x * 64 + (wave & 1) * 32;
  f32x16 acc;
#pragma unroll
  for (int i = 0; i < 16; ++i) acc[i] = 0.f;
#pragma unroll 4
  for (int kc = 0; kc < 256; kc += 16) {
    short8 a = *(const short8*)&Sm[(size_t)(m0 + r31) * 256 + kc + kh * 8];
    short8 b = *(const short8*)&X[(size_t)(n0 + r31) * 256 + kc + kh * 8];
    acc = __builtin_amdgcn_mfma_f32_32x32x16_bf16(a, b, acc, 0, 0, 0);
  }
  if (EPI == 0 || EPI == 1) {
    unsigned short* C = Cb + (size_t)s * NPIX;
#pragma unroll
    for (int reg = 0; reg < 16; ++reg) {
      int gm = m0 + (reg & 3) + 8 * (reg >> 2) + 4 * kh;
      int gn = n0 + r31;
      float v = acc[reg];
      if (EPI == 1) v /= HM[(size_t)gm * 256 + gn];
      C[(size_t)gm * 256 + gn] = f2bf(v);
    }
  } else {
    int b = s / 14, t = s - b * 14;
    const float* hb = xin + (size_t)(b * 15 + t) * NPIX;
    float* H = hout + (size_t)s * NPIX;
#pragma unroll
    for (int reg = 0; reg < 16; ++reg) {
      int gm = m0 + (reg & 3) + 8 * (reg >> 2) + 4 * kh;
      int gn = n0 + r31;
      if (gm < 254 && gn < 254) {
        size_t o = (size_t)(gm + 1) * 256 + (gn + 1);
        float hv = acc[reg] + hb[o];
        H[o] = fminf(fmaxf(hv, -HCLAMP), HCLAMP);
      }
    }
  }
}

// ---------------- pack x -> NHWC(16) bf16 ----------------
__global__ __launch_bounds__(256) void k_pack_x(const float* __restrict__ x,
                                                unsigned short* __restrict__ xp) {
  int e = blockIdx.x * 256 + threadIdx.x;
  int b = e >> 16, p = e & 65535;
  const float* xb = x + (size_t)b * 15 * NPIX + p;
  union { unsigned short u16[16]; uint4 u4[2]; } vv;
#pragma unroll
  for (int c = 0; c < 15; ++c) vv.u16[c] = f2bf(xb[(size_t)c * NPIX]);
  vv.u16[15] = 0;
  uint4* dst = (uint4*)&xp[(size_t)e * 16];
  dst[0] = vv.u4[0];
  dst[1] = vv.u4[1];
}

// ---------------- ALL weight prep in one launch ----------------
// job table: {srcIdx, dstOff, chunks, icpShift, icw, ic0, icReal, ocw, ocReal}
__global__ __launch_bounds__(256) void k_wprep_all(const float* __restrict__ w_in,
                                                   const float* __restrict__ w_hid,
                                                   const float* __restrict__ w_b1,
                                                   const float* __restrict__ w_b21,
                                                   const float* __restrict__ w_b22,
                                                   const float* __restrict__ w_out,
                                                   unsigned short* __restrict__ wtb) {
  const int job = blockIdx.y;
  const float* src;
  int dstOff, chunks, icpShift, icw, ic0, icReal, ocw, ocReal;
  switch (job) {
    case 0: src = w_in;  dstOff = W_IN;  chunks = 5;  icpShift = 4; icw = 15;  ic0 = 0;  icReal = 15; ocw = 64; ocReal = 64; break;
    case 1: src = w_hid; dstOff = W_HID; chunks = 18; icpShift = 6; icw = 64;  ic0 = 0;  icReal = 64; ocw = 64; ocReal = 64; break;
    case 2: src = w_b1;  dstOff = W_B1;  chunks = 18; icpShift = 6; icw = 64;  ic0 = 0;  icReal = 64; ocw = 64; ocReal = 64; break;
    case 3: src = w_b21; dstOff = W_B21; chunks = 18; icpShift = 6; icw = 64;  ic0 = 0;  icReal = 64; ocw = 64; ocReal = 64; break;
    case 4: src = w_b22; dstOff = W_B22; chunks = 18; icpShift = 6; icw = 64;  ic0 = 0;  icReal = 64; ocw = 64; ocReal = 64; break;
    case 5: src = w_out; dstOff = W_O1;  chunks = 18; icpShift = 6; icw = 128; ic0 = 0;  icReal = 64; ocw = 16; ocReal = 15; break;
    default: src = w_out; dstOff = W_O2; chunks = 18; icpShift = 6; icw = 128; ic0 = 64; icReal = 64; ocw = 16; ocReal = 15; break;
  }
  int e = blockIdx.x * 256 + threadIdx.x;
  int total = chunks * 4 * ocw * 8;
  if (e >= total) return;
  int j = e & 7;
  int oc = (e >> 3) % ocw;
  int ckg = e / (8 * ocw);
  int kg = ckg & 3, c = ckg >> 2;
  int Kidx = c * 32 + kg * 8 + j;
  int tap = Kidx >> icpShift;
  int ic = Kidx & ((1 << icpShift) - 1);
  float v = 0.f;
  if (tap < 9 && ic < icReal && oc < ocReal)
    v = src[((size_t)oc * icw + ic0 + ic) * 9 + tap];
  wtb[dstOff + e] = f2bf(v);
}

// ---------------- MFMA 3x3 conv, 64-ch input: LDS tile, global weights ----------------
// Block: 16x16 px, 4 waves x 4 rows, all OCW=NOC*16 out channels per block.
// Full 64-ch 18x18 input tile (41.5KB) in LDS with XOR swizzle g^=(pp&7);
// weights from global (L2-hot, coalesced). NSRC=2: concat conv, staged serially.
// EMODE 0: store acc; 1: store acc * other[oi]
template <int NSRC, int NOC, int OCF, bool RELU, int EMODE>
__global__ __launch_bounds__(256) void k_conv64(const unsigned short* __restrict__ in0,
                                                const unsigned short* __restrict__ in1,
                                                const unsigned short* __restrict__ wt,
                                                const float* __restrict__ bias, int ocReal,
                                                const unsigned short* __restrict__ other,
                                                unsigned short* __restrict__ out) {
  constexpr int OCW = NOC * 16;
  __shared__ unsigned short tile[324 * 64];  // 41472 B

  const int tid = threadIdx.x;
  const int lane = tid & 63, wave = tid >> 6;
  const int cl = lane & 15, kg = lane >> 4;
  const int b = blockIdx.z;
  const int gx0 = blockIdx.x * 16, gy0 = blockIdx.y * 16;

  f32x4 acc[4][NOC];
#pragma unroll
  for (int j = 0; j < NOC; ++j) {
    int oc = j * 16 + cl;
    float bv = (bias != nullptr && oc < ocReal) ? bias[oc] : 0.f;
#pragma unroll
    for (int i = 0; i < 4; ++i) acc[i][j] = (f32x4){bv, bv, bv, bv};
  }

  for (int src = 0; src < NSRC; ++src) {
    const unsigned short* inb = (src ? in1 : in0) + (size_t)b * NPIX * 64;
    const unsigned short* wtp = wt + src * 36864;
    if (src) __syncthreads();
    // ---- stage full 18x18x64 tile (zero halo, swizzled) ----
    for (int c = tid; c < 2592; c += 256) {
      int pp = c >> 3, g = c & 7;
      int ly = pp / 18, lx = pp - ly * 18;
      int iy = gy0 + ly - 1, ix = gx0 + lx - 1;
      uint4 v = make_uint4(0u, 0u, 0u, 0u);
      if (iy >= 0 && iy < 256 && ix >= 0 && ix < 256)
        v = *(const uint4*)&inb[((size_t)iy * 256 + ix) * 64 + g * 8];
      int sw = g ^ (pp & 7);
      *(uint4*)&tile[pp * 64 + sw * 8] = v;
    }
    __syncthreads();
    // ---- compute 18 chunks ----
#pragma unroll 3
    for (int cm = 0; cm < 18; ++cm) {
      const int tap = cm >> 1;
      const int g = (cm & 1) * 4 + kg;
      const int dy = tap / 3, dxx = tap - dy * 3;
      short8 bfr[NOC];
#pragma unroll
      for (int j = 0; j < NOC; ++j)
        bfr[j] = *(const short8*)&wtp[(((size_t)cm * 4 + kg) * OCW + j * 16 + cl) * 8];
      const int tc = cl + dxx;
#pragma unroll
      for (int i = 0; i < 4; ++i) {
        int pp = (wave * 4 + i + dy) * 18 + tc;
        int g2 = g ^ (pp & 7);
        short8 av = *(const short8*)&tile[pp * 64 + g2 * 8];
#pragma unroll
        for (int j = 0; j < NOC; ++j)
          acc[i][j] = __builtin_amdgcn_mfma_f32_16x16x32_bf16(av, bfr[j], acc[i][j], 0, 0, 0);
      }
    }
  }

  const size_t outBase = (size_t)b * NPIX * OCF;
#pragma unroll
  for (int i = 0; i < 4; ++i) {
    int y = gy0 + wave * 4 + i;
#pragma unroll
    for (int j = 0; j < NOC; ++j) {
      int oc = j * 16 + cl;
#pragma unroll
      for (int r = 0; r < 4; ++r) {
        int px = gx0 + kg * 4 + r;
        size_t oi = outBase + ((size_t)y * 256 + px) * OCF + oc;
        float v = acc[i][j][r];
        if (EMODE == 1) v *= bf2f(other[oi]);
        if (RELU) v = fmaxf(v, 0.f);
        out[oi] = f2bf(v);
      }
    }
  }
}

// ---------------- MFMA 3x3 conv, 16-ch input (conv_in), LDS tile + weights ----------------
__global__ __launch_bounds__(256) void k_conv16(const unsigned short* __restrict__ in,
                                                const unsigned short* __restrict__ wt,
                                                const float* __restrict__ bias,
                                                unsigned short* __restrict__ out) {
  __shared__ unsigned short wlds[10240];
  __shared__ unsigned short tile[324 * 16];

  const int tid = threadIdx.x;
  const int lane = tid & 63, wave = tid >> 6;
  const int cl = lane & 15, kg = lane >> 4;
  const int b = blockIdx.z;
  const int gx0 = blockIdx.x * 16, gy0 = blockIdx.y * 16;

  {
    uint4* wl = (uint4*)wlds;
    const uint4* wg = (const uint4*)wt;
    for (int i = tid; i < 1280; i += 256) wl[i] = wg[i];
  }
  const unsigned short* inb = in + (size_t)b * NPIX * 16;
  for (int c = tid; c < 648; c += 256) {
    int pp = c >> 1, g = c & 1;
    int ly = pp / 18, lx = pp - ly * 18;
    int iy = gy0 + ly - 1, ix = gx0 + lx - 1;
    uint4 v = make_uint4(0u, 0u, 0u, 0u);
    if (iy >= 0 && iy < 256 && ix >= 0 && ix < 256)
      v = *(const uint4*)&inb[((size_t)iy * 256 + ix) * 16 + g * 8];
    int sw = g ^ (pp & 1);
    *(uint4*)&tile[pp * 16 + sw * 8] = v;
  }
  __syncthreads();

  f32x4 acc[4][4];
#pragma unroll
  for (int j = 0; j < 4; ++j) {
    float bv = bias[j * 16 + cl];
#pragma unroll
    for (int i = 0; i < 4; ++i) acc[i][j] = (f32x4){bv, bv, bv, bv};
  }

#pragma unroll
  for (int c = 0; c < 5; ++c) {
    int tap = 2 * c + (kg >> 1);             // tap 9: zero weights
    int dy = tap / 3, dxx = tap - dy * 3;
    int gidx = kg & 1;
    short8 bfr[4];
#pragma unroll
    for (int j = 0; j < 4; ++j)
      bfr[j] = *(const short8*)&wlds[((c * 4 + kg) * 64 + j * 16 + cl) * 8];
    int tc = cl + dxx;
#pragma unroll
    for (int i = 0; i < 4; ++i) {
      int tr = wave * 4 + i + dy;
      if (tr > 17) tr = 17;                  // tap 9 only
      int pp = tr * 18 + tc;
      int g2 = gidx ^ (pp & 1);
      short8 av = *(const short8*)&tile[pp * 16 + g2 * 8];
#pragma unroll
      for (int j = 0; j < 4; ++j)
        acc[i][j] = __builtin_amdgcn_mfma_f32_16x16x32_bf16(av, bfr[j], acc[i][j], 0, 0, 0);
    }
  }

  const size_t outBase = (size_t)b * NPIX * 64;
#pragma unroll
  for (int i = 0; i < 4; ++i) {
    int y = gy0 + wave * 4 + i;
#pragma unroll
    for (int j = 0; j < 4; ++j) {
      int oc = j * 16 + cl;
#pragma unroll
      for (int r = 0; r < 4; ++r) {
        int px = gx0 + kg * 4 + r;
        size_t oi = outBase + ((size_t)y * 256 + px) * 64 + oc;
        out[oi] = f2bf(fmaxf(acc[i][j][r], 0.f));
      }
    }
  }
}

// ---------------- reductions ----------------
__global__ __launch_bounds__(256) void k_red_dyn(const float* __restrict__ x,
                                                 const float* __restrict__ h,
                                                 double* __restrict__ part) {
  double sum = 0.0;
  for (int e = blockIdx.x * 256 + threadIdx.x; e < NS * NPIX; e += NB_RED * 256) {
    int s = e >> 16, p = e & 65535;
    int b = s / 14, t = s - b * 14;
    float d = x[(size_t)(b * 15 + t + 1) * NPIX + p] - h[e];
    sum += (double)d * (double)d;
  }
  for (int o = 32; o > 0; o >>= 1) sum += __shfl_down(sum, o);
  __shared__ double sw[4];
  int lane = threadIdx.x & 63, wid = threadIdx.x >> 6;
  if (lane == 0) sw[wid] = sum;
  __syncthreads();
  if (threadIdx.x == 0) part[blockIdx.x] = sw[0] + sw[1] + sw[2] + sw[3];
}

__global__ __launch_bounds__(256) void k_red_ae(const float* __restrict__ x,
                                                const unsigned short* __restrict__ xa,
                                                double* __restrict__ part) {
  double sum = 0.0;
  for (int e = blockIdx.x * 256 + threadIdx.x; e < 60 * NPIX; e += NB_RED * 256) {
    int b = e / (15 * NPIX);
    int r2 = e - b * 15 * NPIX;
    int c = r2 >> 16, p = r2 & 65535;
    float xav = bf2f(xa[((size_t)b * NPIX + p) * 16 + c]);
    float d = x[e] - xav;
    sum += (double)d * (double)d;
  }
  for (int o = 32; o > 0; o >>= 1) sum += __shfl_down(sum, o);
  __shared__ double sw[4];
  int lane = threadIdx.x & 63, wid = threadIdx.x >> 6;
  if (lane == 0) sw[wid] = sum;
  __syncthreads();
  if (threadIdx.x == 0) part[NB_RED + blockIdx.x] = sw[0] + sw[1] + sw[2] + sw[3];
}

__global__ __launch_bounds__(256) void k_final(const double* __restrict__ part,
                                               float* __restrict__ out) {
  double s1 = 0.0, s2 = 0.0;
  for (int i = threadIdx.x; i < NB_RED; i += 256) {
    s1 += part[i];
    s2 += part[NB_RED + i];
  }
  for (int o = 32; o > 0; o >>= 1) {
    s1 += __shfl_down(s1, o);
    s2 += __shfl_down(s2, o);
  }
  __shared__ double a1[4], a2[4];
  int lane = threadIdx.x & 63, wid = threadIdx.x >> 6;
  if (lane == 0) { a1[wid] = s1; a2[wid] = s2; }
  __syncthreads();
  if (threadIdx.x == 0) {
    double v = (a1[0] + a1[1] + a1[2] + a1[3]) / (double)(NS * NPIX)
             + (a2[0] + a2[1] + a2[2] + a2[3]) / (double)(60 * NPIX);
    if (!(v == v)) v = 0.0;
    if (v > 1.0e30) v = 1.0e30;
    if (v < -1.0e30) v = -1.0e30;
    out[0] = (float)v;
  }
}

// ---------------- launcher ----------------
extern "C" void kernel_launch(void* const* d_in, const int* in_sizes, int n_in,
                              void* d_out, int out_size, void* d_ws, size_t ws_size,
                              hipStream_t stream) {
  (void)in_sizes; (void)n_in; (void)out_size; (void)ws_size;
  const float* x     = (const float*)d_in[0];
  const float* w_in  = (const float*)d_in[1];
  const float* b_in  = (const float*)d_in[2];
  const float* w_hid = (const float*)d_in[3];
  const float* b_hid = (const float*)d_in[4];
  const float* w_b1  = (const float*)d_in[5];
  const float* b_b1  = (const float*)d_in[6];
  const float* w_b21 = (const float*)d_in[7];
  const float* b_b21 = (const float*)d_in[8];
  const float* w_b22 = (const float*)d_in[9];
  const float* b_b22 = (const float*)d_in[10];
  const float* w_out = (const float*)d_in[11];
  const float* b_out = (const float*)d_in[12];
  float* ws = (float*)d_ws;
  float* out = (float*)d_out;

  double mc = 0.0;
  for (int k = 0; k < 256; ++k) mc += cos((32.0 + 0.05 * k) * D_PI / 180.0);
  mc /= 256.0;
  float DXf = (float)(0.5 * (5550.0 + 5550.0 * mc));
  float dx2 = DXf * DXf;
  float gf  = (float)(9.81 / 1e-4);
  float ngf = (float)(-9.81 / 1e-4);
  float gfc = (float)(9.81 * 1e-4 / (2.7 * 2.7));
  float fdx = 4.0f * DXf;
  float cc  = 1.0f / (6.0f * DXf);
  float dtf = 21600.0f;

  double* part = (double*)d_ws;
  unsigned short* S  = (unsigned short*)(ws + OFF_S);
  float* HM = ws + OFF_HM;
  float* h  = ws + OFF_H;
  float* q0 = ws + OFF_Q0;
  float* q1 = ws + OFF_Q1;
  float* qb = ws + OFF_QB;
  unsigned short* tA = (unsigned short*)(ws + OFF_TA);
  unsigned short* U  = (unsigned short*)(ws + OFF_U);
  unsigned short* V  = (unsigned short*)(ws + OFF_V);
  unsigned short* wtb = (unsigned short*)(ws + OFF_WT);

  k_dst_init<<<dim3(256), dim3(256), 0, stream>>>(S, HM, dx2);
  k_wprep_all<<<dim3(144, 7), dim3(256), 0, stream>>>(w_in, w_hid, w_b1, w_b21, w_b22, w_out, wtb);
  k_qg_init<<<dim3(NS * NPIX / 256), dim3(256), 0, stream>>>(x, h, q0, qb, dx2, gf, gfc);

  float* qc = q0;
  float* qn = q1;
  dim3 gg(4, 4, NS);
  for (int step = 0; step < 4; ++step) {
    k_qrhs<<<dim3(NS * NPIX / 256), dim3(256), 0, stream>>>(h, qc, qb, qn, tA,
                                                            ngf, gf, fdx, cc, dtf);
    k_gemm_mfma<0><<<gg, dim3(256), 0, stream>>>(S, tA, U, nullptr, nullptr, nullptr);
    k_gemm_mfma<1><<<gg, dim3(256), 0, stream>>>(S, U, V, HM, nullptr, nullptr);
    k_gemm_mfma<0><<<gg, dim3(256), 0, stream>>>(S, V, U, nullptr, nullptr, nullptr);
    k_gemm_mfma<2><<<gg, dim3(256), 0, stream>>>(S, U, nullptr, nullptr, x, h);
    float* tmp = qc; qc = qn; qn = tmp;
  }
  k_red_dyn<<<dim3(NB_RED), dim3(256), 0, stream>>>(x, h, part);

  unsigned short* xp = (unsigned short*)(ws + OFF_XP);
  unsigned short* z1 = (unsigned short*)(ws + OFF_Z1);
  unsigned short* z2 = (unsigned short*)(ws + OFF_Z2);
  unsigned short* bc = (unsigned short*)(ws + OFF_BC);
  unsigned short* xa = (unsigned short*)(ws + OFF_XA);

  k_pack_x<<<dim3(4 * NPIX / 256), dim3(256), 0, stream>>>(x, xp);

  dim3 cg4(16, 16, 4);
  // conv_in: xp(16) -> z1 (relu on store)
  k_conv16<<<cg4, dim3(256), 0, stream>>>(xp, wtb + W_IN, b_in, z1);
  // hid: z1 -> z2
  k_conv64<1, 4, 64, false, 0><<<cg4, dim3(256), 0, stream>>>(
      z1, z1, wtb + W_HID, b_hid, 64, nullptr, z2);
  // b1: z2 -> z1
  k_conv64<1, 4, 64, false, 0><<<cg4, dim3(256), 0, stream>>>(
      z2, z2, wtb + W_B1, b_b1, 64, nullptr, z1);
  // b21: z2 -> bc
  k_conv64<1, 4, 64, false, 0><<<cg4, dim3(256), 0, stream>>>(
      z2, z2, wtb + W_B21, b_b21, 64, nullptr, bc);
  // b22: z2 -> bc (multiply by other=bc)
  k_conv64<1, 4, 64, false, 1><<<cg4, dim3(256), 0, stream>>>(
      z2, z2, wtb + W_B22, b_b22, 64, bc, bc);
  // out: concat(z1, bc) -> xa (dual source, 16 oc; W_O1/W_O2 contiguous)
  k_conv64<2, 1, 16, false, 0><<<cg4, dim3(256), 0, stream>>>(
      z1, bc, wtb + W_O1, b_out, 15, nullptr, xa);

  k_red_ae<<<dim3(NB_RED), dim3(256), 0, stream>>>(x, xa, part);
  k_final<<<dim3(1), dim3(256), 0, stream>>>(part, out);
}

// Round 8
// 525.785 us; speedup vs baseline: 1.3028x; 1.1890x over previous
//
#include <hip/hip_runtime.h>
#include <math.h>

#define NS 56        // B*(T-1)
#define NPIX 65536   // 256*256
#define NB_RED 1024

static constexpr double D_PI = 3.14159265358979323846;

typedef __attribute__((ext_vector_type(8))) short short8;
typedef __attribute__((ext_vector_type(4))) float f32x4;
typedef __attribute__((ext_vector_type(16))) float f32x16;

__device__ inline unsigned short f2bf(float f) {
  union { float f; unsigned int u; } v; v.f = f;
  unsigned int r = v.u + 0x7FFFu + ((v.u >> 16) & 1u);
  return (unsigned short)(r >> 16);
}
__device__ inline float bf2f(unsigned short b) {
  union { float f; unsigned int u; } v; v.u = ((unsigned int)b) << 16;
  return v.f;
}

// ---------------- workspace layout (float offsets) ----------------
#define OFF_PART 0                        // 2048 doubles
#define OFF_S    4096
#define OFF_HM   (OFF_S + 32768)
#define OFF_H    (OFF_HM + 65536)
#define SLC      (NS * NPIX)
#define OFF_Q0   (OFF_H + SLC)
#define OFF_Q1   (OFF_Q0 + SLC)
#define OFF_QB   (OFF_Q1 + SLC)
#define OFF_TA   (OFF_QB + SLC)
#define OFF_U    (OFF_TA + SLC / 2)
#define OFF_V    (OFF_U + SLC / 2)
// conv phase reuses QG region
#define OFF_XP   OFF_H
#define OFF_Z1   (OFF_XP + 2097152)
#define OFF_Z2   (OFF_Z1 + 8388608)
#define OFF_BC   (OFF_Z2 + 8388608)
#define OFF_XA   (OFF_BC + 8388608)
#define OFF_WT   (OFF_XA + 2097152)
// weight regions in SHORT offsets from wtb (full 64-oc layouts)
#define W_IN    0                         // 5*4*64*8   = 10240
#define W_HID   10240                     // 18*4*64*8  = 36864
#define W_B1    47104
#define W_B21   83968
#define W_B22   120832
#define W_O1    157696                    // 18*4*16*8  = 9216
#define W_O2    166912

#define QCLAMP 1.0e12f
#define HCLAMP 1.0e15f

// ---------------- init: DST matrix (bf16) + Helmholtz eigenvalues ----------------
__global__ __launch_bounds__(256) void k_dst_init(unsigned short* __restrict__ S,
                                                  float* __restrict__ HM, float dx2f) {
  int idx = blockIdx.x * 256 + threadIdx.x;
  int i = idx >> 8, j = idx & 255;
  float sv = 0.f, hv = 1.f;
  if (i < 254 && j < 254) {
    double arg = D_PI * (double)((i + 1) * (j + 1)) / 255.0;
    sv = (float)((2.0 / sqrt(510.0)) * sin(arg));
    double la = 2.0 * (cos(D_PI * (double)(i + 1) / 255.0) - 1.0) / (double)dx2f
              + 2.0 * (cos(D_PI * (double)(j + 1) / 255.0) - 1.0) / (double)dx2f;
    hv = (float)((9.81 / 1e-4) * la - 9.81 * 1e-4 / (2.7 * 2.7));
  }
  S[idx] = f2bf(sv);
  HM[idx] = hv;
}

// ---------------- QG init ----------------
__global__ __launch_bounds__(256) void k_qg_init(const float* __restrict__ x,
                                                 float* __restrict__ h,
                                                 float* __restrict__ q,
                                                 float* __restrict__ qb,
                                                 float dx2, float gf, float gfc) {
  int idx = blockIdx.x * 256 + threadIdx.x;
  int s = idx >> 16, p = idx & 65535;
  int y = p >> 8, xx = p & 255;
  int b = s / 14, t = s - b * 14;
  const float* hb = x + (size_t)(b * 15 + t) * NPIX;
  float hc = hb[p];
  float qv;
  if (y >= 2 && y <= 252 && xx >= 2 && xx <= 252) {
    qv = gf * ((hb[p + 256] + hb[p - 256] - 2.f * hc) / dx2
             + (hb[p + 1] + hb[p - 1] - 2.f * hc) / dx2) - gfc * hc;
  } else {
    qv = -gfc * hc;
  }
  h[idx] = hc;
  q[idx] = qv;
  qb[idx] = qv;
}

// ---------------- q1 update + padded bf16 qin ----------------
__global__ __launch_bounds__(256) void k_qrhs(const float* __restrict__ h,
                                              const float* __restrict__ qc,
                                              const float* __restrict__ qb,
                                              float* __restrict__ qn,
                                              unsigned short* __restrict__ tA,
                                              float ngf, float pgf, float fdx,
                                              float cc, float dtf) {
  int idx = blockIdx.x * 256 + threadIdx.x;
  int s = idx >> 16, p = idx & 65535;
  int y = p >> 8, xx = p & 255;
  const float* H = h + (size_t)s * NPIX;
  const float* Q = qc + (size_t)s * NPIX;
  float qv = Q[p];
  float q1 = qv;
  if (y >= 2 && y <= 252 && xx >= 2 && xx <= 252) {
    float hSW = H[p + 255], hS = H[p + 256], hSE = H[p + 257];
    float hNW = H[p - 257], hN = H[p - 256], hNE = H[p - 255];
    float hW = H[p - 1], hE = H[p + 1];
    float uA = ngf * (hSW + hS - hN - hNW) / fdx;
    float uB = ngf * (hS + hSE - hNE - hN) / fdx;
    float vA = pgf * (hE + hNE - hNW - hW) / fdx;
    float vB = pgf * (hSE + hE - hW - hSW) / fdx;
    float uT = 0.5f * (uA + uB);
    float vT = 0.5f * (vA + vB);
    float up = fmaxf(uT, 0.f), um = fminf(uT, 0.f);
    float vp = fmaxf(vT, 0.f), vm = fminf(vT, 0.f);
    float Q0 = qv;
    float QE = Q[p + 1], QW = Q[p - 1], QEE = Q[p + 2], QWW = Q[p - 2];
    float QS = Q[p + 256], QN = Q[p - 256], QSS = Q[p + 512], QNN = Q[p - 512];
    float r = -up * cc * (2.f * QE + 3.f * Q0 - 6.f * QW + QWW)
            + um * cc * (QEE - 6.f * QE + 3.f * Q0 + 2.f * QW)
            - vp * cc * (2.f * QS + 3.f * Q0 - 6.f * QN + QNN)
            + vm * cc * (QSS - 6.f * QS + 3.f * Q0 + 2.f * QN);
    q1 = qv + dtf * r;
    q1 = fminf(fmaxf(q1, -QCLAMP), QCLAMP);
  }
  qn[idx] = q1;
  int wy = (y == 0) ? 254 : ((y == 255) ? 255 : y - 1);
  int wx = (xx == 0) ? 254 : ((xx == 255) ? 255 : xx - 1);
  float val = 0.f;
  if (y >= 1 && y <= 254 && xx >= 1 && xx <= 254) val = q1 - qb[idx];
  tA[(size_t)s * NPIX + wy * 256 + wx] = f2bf(val);
}

// ---------------- fused half-solve: one dstI2D (two chained multiplies) ----------------
// Block (s=blockIdx.x, q=blockIdx.y), 512 thr = 8 waves.
// Phase A: U_q[a][b] = sum_c S[32q+a][c]*X[b][c], a in [0,32), b in [0,256)
//          wave w computes the 32x32 tile with b0 = 32w -> LDS (16 KB, swizzled).
// Phase B: C[m][n] = sum_b S[m][b]*U_q[n-32q][b], m in [0,256), n in [32q,+32)
//          wave w computes m0 = 32w.
// EPI 0: out = (C/HM) bf16 (first dstI2D, Helmholtz divide)
// EPI 1: h[interior] = clamp(C + hb) f32 (second dstI2D + add background)
// grid (56, 8): a slice's 8 blocks land on one XCD (56%8==0) for L2 reuse.
template <int EPI>
__global__ __launch_bounds__(512) void k_solve(const unsigned short* __restrict__ Sm,
                                               const unsigned short* __restrict__ Xb,
                                               unsigned short* __restrict__ Ob,
                                               const float* __restrict__ HM,
                                               const float* __restrict__ xin,
                                               float* __restrict__ hout) {
  __shared__ unsigned short Ul[32 * 256];  // 16 KB
  const int s = blockIdx.x, q = blockIdx.y;
  const unsigned short* X = Xb + (size_t)s * NPIX;
  const int lane = threadIdx.x & 63, w = threadIdx.x >> 6;
  const int r31 = lane & 31, kh = lane >> 5;

  // ---- Phase A ----
  f32x16 acc;
#pragma unroll
  for (int i = 0; i < 16; ++i) acc[i] = 0.f;
  {
    const int ar = (32 * q + r31) * 256;   // S row for A
    const int br = (32 * w + r31) * 256;   // X row for B
#pragma unroll 4
    for (int kc = 0; kc < 256; kc += 16) {
      short8 a = *(const short8*)&Sm[ar + kc + kh * 8];
      short8 b = *(const short8*)&X[br + kc + kh * 8];
      acc = __builtin_amdgcn_mfma_f32_32x32x16_bf16(a, b, acc, 0, 0, 0);
    }
  }
  {
    const int col = 32 * w + r31;
    const int g = col >> 3, c7 = col & 7;
#pragma unroll
    for (int reg = 0; reg < 16; ++reg) {
      int i = (reg & 3) + 8 * (reg >> 2) + 4 * kh;
      Ul[i * 256 + (((g ^ (i & 7)) << 3) | c7)] = f2bf(acc[reg]);
    }
  }
  __syncthreads();

  // ---- Phase B ----
  f32x16 acc2;
#pragma unroll
  for (int i = 0; i < 16; ++i) acc2[i] = 0.f;
  {
    const int ar = (32 * w + r31) * 256;   // S row for A (m)
    const int urow = r31 * 256;            // U_q local row (n)
    const int x7 = (r31 & 7);
#pragma unroll 4
    for (int kc = 0; kc < 256; kc += 16) {
      int g0 = (kc >> 3) + kh;
      short8 a = *(const short8*)&Sm[ar + kc + kh * 8];
      short8 b = *(const short8*)&Ul[urow + ((g0 ^ x7) << 3)];
      acc2 = __builtin_amdgcn_mfma_f32_32x32x16_bf16(a, b, acc2, 0, 0, 0);
    }
  }
  const int gn = 32 * q + r31;
  if (EPI == 0) {
    unsigned short* O = Ob + (size_t)s * NPIX;
#pragma unroll
    for (int reg = 0; reg < 16; ++reg) {
      int gm = 32 * w + (reg & 3) + 8 * (reg >> 2) + 4 * kh;
      O[(size_t)gm * 256 + gn] = f2bf(acc2[reg] / HM[(size_t)gm * 256 + gn]);
    }
  } else {
    int b = s / 14, t = s - b * 14;
    const float* hb = xin + (size_t)(b * 15 + t) * NPIX;
    float* H = hout + (size_t)s * NPIX;
    if (gn < 254) {
#pragma unroll
      for (int reg = 0; reg < 16; ++reg) {
        int gm = 32 * w + (reg & 3) + 8 * (reg >> 2) + 4 * kh;
        if (gm < 254) {
          size_t o = (size_t)(gm + 1) * 256 + (gn + 1);
          float hv = acc2[reg] + hb[o];
          H[o] = fminf(fmaxf(hv, -HCLAMP), HCLAMP);
        }
      }
    }
  }
}

// ---------------- pack x -> NHWC(16) bf16 ----------------
__global__ __launch_bounds__(256) void k_pack_x(const float* __restrict__ x,
                                                unsigned short* __restrict__ xp) {
  int e = blockIdx.x * 256 + threadIdx.x;
  int b = e >> 16, p = e & 65535;
  const float* xb = x + (size_t)b * 15 * NPIX + p;
  union { unsigned short u16[16]; uint4 u4[2]; } vv;
#pragma unroll
  for (int c = 0; c < 15; ++c) vv.u16[c] = f2bf(xb[(size_t)c * NPIX]);
  vv.u16[15] = 0;
  uint4* dst = (uint4*)&xp[(size_t)e * 16];
  dst[0] = vv.u4[0];
  dst[1] = vv.u4[1];
}

// ---------------- ALL weight prep in one launch ----------------
__global__ __launch_bounds__(256) void k_wprep_all(const float* __restrict__ w_in,
                                                   const float* __restrict__ w_hid,
                                                   const float* __restrict__ w_b1,
                                                   const float* __restrict__ w_b21,
                                                   const float* __restrict__ w_b22,
                                                   const float* __restrict__ w_out,
                                                   unsigned short* __restrict__ wtb) {
  const int job = blockIdx.y;
  const float* src;
  int dstOff, chunks, icpShift, icw, ic0, icReal, ocw, ocReal;
  switch (job) {
    case 0: src = w_in;  dstOff = W_IN;  chunks = 5;  icpShift = 4; icw = 15;  ic0 = 0;  icReal = 15; ocw = 64; ocReal = 64; break;
    case 1: src = w_hid; dstOff = W_HID; chunks = 18; icpShift = 6; icw = 64;  ic0 = 0;  icReal = 64; ocw = 64; ocReal = 64; break;
    case 2: src = w_b1;  dstOff = W_B1;  chunks = 18; icpShift = 6; icw = 64;  ic0 = 0;  icReal = 64; ocw = 64; ocReal = 64; break;
    case 3: src = w_b21; dstOff = W_B21; chunks = 18; icpShift = 6; icw = 64;  ic0 = 0;  icReal = 64; ocw = 64; ocReal = 64; break;
    case 4: src = w_b22; dstOff = W_B22; chunks = 18; icpShift = 6; icw = 64;  ic0 = 0;  icReal = 64; ocw = 64; ocReal = 64; break;
    case 5: src = w_out; dstOff = W_O1;  chunks = 18; icpShift = 6; icw = 128; ic0 = 0;  icReal = 64; ocw = 16; ocReal = 15; break;
    default: src = w_out; dstOff = W_O2; chunks = 18; icpShift = 6; icw = 128; ic0 = 64; icReal = 64; ocw = 16; ocReal = 15; break;
  }
  int e = blockIdx.x * 256 + threadIdx.x;
  int total = chunks * 4 * ocw * 8;
  if (e >= total) return;
  int j = e & 7;
  int oc = (e >> 3) % ocw;
  int ckg = e / (8 * ocw);
  int kg = ckg & 3, c = ckg >> 2;
  int Kidx = c * 32 + kg * 8 + j;
  int tap = Kidx >> icpShift;
  int ic = Kidx & ((1 << icpShift) - 1);
  float v = 0.f;
  if (tap < 9 && ic < icReal && oc < ocReal)
    v = src[((size_t)oc * icw + ic0 + ic) * 9 + tap];
  wtb[dstOff + e] = f2bf(v);
}

// ---------------- MFMA 3x3 conv, 64-ch input: LDS tile, global weights ----------------
template <int NSRC, int NOC, int OCF, bool RELU, int EMODE>
__global__ __launch_bounds__(256) void k_conv64(const unsigned short* __restrict__ in0,
                                                const unsigned short* __restrict__ in1,
                                                const unsigned short* __restrict__ wt,
                                                const float* __restrict__ bias, int ocReal,
                                                const unsigned short* __restrict__ other,
                                                unsigned short* __restrict__ out) {
  constexpr int OCW = NOC * 16;
  __shared__ unsigned short tile[324 * 64];  // 41472 B

  const int tid = threadIdx.x;
  const int lane = tid & 63, wave = tid >> 6;
  const int cl = lane & 15, kg = lane >> 4;
  const int b = blockIdx.z;
  const int gx0 = blockIdx.x * 16, gy0 = blockIdx.y * 16;

  f32x4 acc[4][NOC];
#pragma unroll
  for (int j = 0; j < NOC; ++j) {
    int oc = j * 16 + cl;
    float bv = (bias != nullptr && oc < ocReal) ? bias[oc] : 0.f;
#pragma unroll
    for (int i = 0; i < 4; ++i) acc[i][j] = (f32x4){bv, bv, bv, bv};
  }

  for (int src = 0; src < NSRC; ++src) {
    const unsigned short* inb = (src ? in1 : in0) + (size_t)b * NPIX * 64;
    const unsigned short* wtp = wt + src * 36864;
    if (src) __syncthreads();
    for (int c = tid; c < 2592; c += 256) {
      int pp = c >> 3, g = c & 7;
      int ly = pp / 18, lx = pp - ly * 18;
      int iy = gy0 + ly - 1, ix = gx0 + lx - 1;
      uint4 v = make_uint4(0u, 0u, 0u, 0u);
      if (iy >= 0 && iy < 256 && ix >= 0 && ix < 256)
        v = *(const uint4*)&inb[((size_t)iy * 256 + ix) * 64 + g * 8];
      int sw = g ^ (pp & 7);
      *(uint4*)&tile[pp * 64 + sw * 8] = v;
    }
    __syncthreads();
#pragma unroll 3
    for (int cm = 0; cm < 18; ++cm) {
      const int tap = cm >> 1;
      const int g = (cm & 1) * 4 + kg;
      const int dy = tap / 3, dxx = tap - dy * 3;
      short8 bfr[NOC];
#pragma unroll
      for (int j = 0; j < NOC; ++j)
        bfr[j] = *(const short8*)&wtp[(((size_t)cm * 4 + kg) * OCW + j * 16 + cl) * 8];
      const int tc = cl + dxx;
#pragma unroll
      for (int i = 0; i < 4; ++i) {
        int pp = (wave * 4 + i + dy) * 18 + tc;
        int g2 = g ^ (pp & 7);
        short8 av = *(const short8*)&tile[pp * 64 + g2 * 8];
#pragma unroll
        for (int j = 0; j < NOC; ++j)
          acc[i][j] = __builtin_amdgcn_mfma_f32_16x16x32_bf16(av, bfr[j], acc[i][j], 0, 0, 0);
      }
    }
  }

  const size_t outBase = (size_t)b * NPIX * OCF;
#pragma unroll
  for (int i = 0; i < 4; ++i) {
    int y = gy0 + wave * 4 + i;
#pragma unroll
    for (int j = 0; j < NOC; ++j) {
      int oc = j * 16 + cl;
#pragma unroll
      for (int r = 0; r < 4; ++r) {
        int px = gx0 + kg * 4 + r;
        size_t oi = outBase + ((size_t)y * 256 + px) * OCF + oc;
        float v = acc[i][j][r];
        if (EMODE == 1) v *= bf2f(other[oi]);
        if (RELU) v = fmaxf(v, 0.f);
        out[oi] = f2bf(v);
      }
    }
  }
}

// ---------------- MFMA 3x3 conv, 16-ch input (conv_in), LDS tile + weights ----------------
__global__ __launch_bounds__(256) void k_conv16(const unsigned short* __restrict__ in,
                                                const unsigned short* __restrict__ wt,
                                                const float* __restrict__ bias,
                                                unsigned short* __restrict__ out) {
  __shared__ unsigned short wlds[10240];
  __shared__ unsigned short tile[324 * 16];

  const int tid = threadIdx.x;
  const int lane = tid & 63, wave = tid >> 6;
  const int cl = lane & 15, kg = lane >> 4;
  const int b = blockIdx.z;
  const int gx0 = blockIdx.x * 16, gy0 = blockIdx.y * 16;

  {
    uint4* wl = (uint4*)wlds;
    const uint4* wg = (const uint4*)wt;
    for (int i = tid; i < 1280; i += 256) wl[i] = wg[i];
  }
  const unsigned short* inb = in + (size_t)b * NPIX * 16;
  for (int c = tid; c < 648; c += 256) {
    int pp = c >> 1, g = c & 1;
    int ly = pp / 18, lx = pp - ly * 18;
    int iy = gy0 + ly - 1, ix = gx0 + lx - 1;
    uint4 v = make_uint4(0u, 0u, 0u, 0u);
    if (iy >= 0 && iy < 256 && ix >= 0 && ix < 256)
      v = *(const uint4*)&inb[((size_t)iy * 256 + ix) * 16 + g * 8];
    int sw = g ^ (pp & 1);
    *(uint4*)&tile[pp * 16 + sw * 8] = v;
  }
  __syncthreads();

  f32x4 acc[4][4];
#pragma unroll
  for (int j = 0; j < 4; ++j) {
    float bv = bias[j * 16 + cl];
#pragma unroll
    for (int i = 0; i < 4; ++i) acc[i][j] = (f32x4){bv, bv, bv, bv};
  }

#pragma unroll
  for (int c = 0; c < 5; ++c) {
    int tap = 2 * c + (kg >> 1);
    int dy = tap / 3, dxx = tap - dy * 3;
    int gidx = kg & 1;
    short8 bfr[4];
#pragma unroll
    for (int j = 0; j < 4; ++j)
      bfr[j] = *(const short8*)&wlds[((c * 4 + kg) * 64 + j * 16 + cl) * 8];
    int tc = cl + dxx;
#pragma unroll
    for (int i = 0; i < 4; ++i) {
      int tr = wave * 4 + i + dy;
      if (tr > 17) tr = 17;
      int pp = tr * 18 + tc;
      int g2 = gidx ^ (pp & 1);
      short8 av = *(const short8*)&tile[pp * 16 + g2 * 8];
#pragma unroll
      for (int j = 0; j < 4; ++j)
        acc[i][j] = __builtin_amdgcn_mfma_f32_16x16x32_bf16(av, bfr[j], acc[i][j], 0, 0, 0);
    }
  }

  const size_t outBase = (size_t)b * NPIX * 64;
#pragma unroll
  for (int i = 0; i < 4; ++i) {
    int y = gy0 + wave * 4 + i;
#pragma unroll
    for (int j = 0; j < 4; ++j) {
      int oc = j * 16 + cl;
#pragma unroll
      for (int r = 0; r < 4; ++r) {
        int px = gx0 + kg * 4 + r;
        size_t oi = outBase + ((size_t)y * 256 + px) * 64 + oc;
        out[oi] = f2bf(fmaxf(acc[i][j][r], 0.f));
      }
    }
  }
}

// ---------------- reductions ----------------
__global__ __launch_bounds__(256) void k_red_dyn(const float* __restrict__ x,
                                                 const float* __restrict__ h,
                                                 double* __restrict__ part) {
  double sum = 0.0;
  for (int e = blockIdx.x * 256 + threadIdx.x; e < NS * NPIX; e += NB_RED * 256) {
    int s = e >> 16, p = e & 65535;
    int b = s / 14, t = s - b * 14;
    float d = x[(size_t)(b * 15 + t + 1) * NPIX + p] - h[e];
    sum += (double)d * (double)d;
  }
  for (int o = 32; o > 0; o >>= 1) sum += __shfl_down(sum, o);
  __shared__ double sw[4];
  int lane = threadIdx.x & 63, wid = threadIdx.x >> 6;
  if (lane == 0) sw[wid] = sum;
  __syncthreads();
  if (threadIdx.x == 0) part[blockIdx.x] = sw[0] + sw[1] + sw[2] + sw[3];
}

__global__ __launch_bounds__(256) void k_red_ae(const float* __restrict__ x,
                                                const unsigned short* __restrict__ xa,
                                                double* __restrict__ part) {
  double sum = 0.0;
  for (int e = blockIdx.x * 256 + threadIdx.x; e < 60 * NPIX; e += NB_RED * 256) {
    int b = e / (15 * NPIX);
    int r2 = e - b * 15 * NPIX;
    int c = r2 >> 16, p = r2 & 65535;
    float xav = bf2f(xa[((size_t)b * NPIX + p) * 16 + c]);
    float d = x[e] - xav;
    sum += (double)d * (double)d;
  }
  for (int o = 32; o > 0; o >>= 1) sum += __shfl_down(sum, o);
  __shared__ double sw[4];
  int lane = threadIdx.x & 63, wid = threadIdx.x >> 6;
  if (lane == 0) sw[wid] = sum;
  __syncthreads();
  if (threadIdx.x == 0) part[NB_RED + blockIdx.x] = sw[0] + sw[1] + sw[2] + sw[3];
}

__global__ __launch_bounds__(256) void k_final(const double* __restrict__ part,
                                               float* __restrict__ out) {
  double s1 = 0.0, s2 = 0.0;
  for (int i = threadIdx.x; i < NB_RED; i += 256) {
    s1 += part[i];
    s2 += part[NB_RED + i];
  }
  for (int o = 32; o > 0; o >>= 1) {
    s1 += __shfl_down(s1, o);
    s2 += __shfl_down(s2, o);
  }
  __shared__ double a1[4], a2[4];
  int lane = threadIdx.x & 63, wid = threadIdx.x >> 6;
  if (lane == 0) { a1[wid] = s1; a2[wid] = s2; }
  __syncthreads();
  if (threadIdx.x == 0) {
    double v = (a1[0] + a1[1] + a1[2] + a1[3]) / (double)(NS * NPIX)
             + (a2[0] + a2[1] + a2[2] + a2[3]) / (double)(60 * NPIX);
    if (!(v == v)) v = 0.0;
    if (v > 1.0e30) v = 1.0e30;
    if (v < -1.0e30) v = -1.0e30;
    out[0] = (float)v;
  }
}

// ---------------- launcher ----------------
extern "C" void kernel_launch(void* const* d_in, const int* in_sizes, int n_in,
                              void* d_out, int out_size, void* d_ws, size_t ws_size,
                              hipStream_t stream) {
  (void)in_sizes; (void)n_in; (void)out_size; (void)ws_size;
  const float* x     = (const float*)d_in[0];
  const float* w_in  = (const float*)d_in[1];
  const float* b_in  = (const float*)d_in[2];
  const float* w_hid = (const float*)d_in[3];
  const float* b_hid = (const float*)d_in[4];
  const float* w_b1  = (const float*)d_in[5];
  const float* b_b1  = (const float*)d_in[6];
  const float* w_b21 = (const float*)d_in[7];
  const float* b_b21 = (const float*)d_in[8];
  const float* w_b22 = (const float*)d_in[9];
  const float* b_b22 = (const float*)d_in[10];
  const float* w_out = (const float*)d_in[11];
  const float* b_out = (const float*)d_in[12];
  float* ws = (float*)d_ws;
  float* out = (float*)d_out;

  double mc = 0.0;
  for (int k = 0; k < 256; ++k) mc += cos((32.0 + 0.05 * k) * D_PI / 180.0);
  mc /= 256.0;
  float DXf = (float)(0.5 * (5550.0 + 5550.0 * mc));
  float dx2 = DXf * DXf;
  float gf  = (float)(9.81 / 1e-4);
  float ngf = (float)(-9.81 / 1e-4);
  float gfc = (float)(9.81 * 1e-4 / (2.7 * 2.7));
  float fdx = 4.0f * DXf;
  float cc  = 1.0f / (6.0f * DXf);
  float dtf = 21600.0f;

  double* part = (double*)d_ws;
  unsigned short* S  = (unsigned short*)(ws + OFF_S);
  float* HM = ws + OFF_HM;
  float* h  = ws + OFF_H;
  float* q0 = ws + OFF_Q0;
  float* q1 = ws + OFF_Q1;
  float* qb = ws + OFF_QB;
  unsigned short* tA = (unsigned short*)(ws + OFF_TA);
  unsigned short* A1 = (unsigned short*)(ws + OFF_U);
  unsigned short* wtb = (unsigned short*)(ws + OFF_WT);

  k_dst_init<<<dim3(256), dim3(256), 0, stream>>>(S, HM, dx2);
  k_wprep_all<<<dim3(144, 7), dim3(256), 0, stream>>>(w_in, w_hid, w_b1, w_b21, w_b22, w_out, wtb);
  k_qg_init<<<dim3(NS * NPIX / 256), dim3(256), 0, stream>>>(x, h, q0, qb, dx2, gf, gfc);

  float* qc = q0;
  float* qn = q1;
  dim3 sg(56, 8);
  for (int step = 0; step < 4; ++step) {
    k_qrhs<<<dim3(NS * NPIX / 256), dim3(256), 0, stream>>>(h, qc, qb, qn, tA,
                                                            ngf, gf, fdx, cc, dtf);
    // A1 = dstI2D(qin) / HELM
    k_solve<0><<<sg, dim3(512), 0, stream>>>(S, tA, A1, HM, nullptr, nullptr);
    // h[interior] = clamp(dstI2D(A1) + hb)
    k_solve<1><<<sg, dim3(512), 0, stream>>>(S, A1, nullptr, nullptr, x, h);
    float* tmp = qc; qc = qn; qn = tmp;
  }
  k_red_dyn<<<dim3(NB_RED), dim3(256), 0, stream>>>(x, h, part);

  unsigned short* xp = (unsigned short*)(ws + OFF_XP);
  unsigned short* z1 = (unsigned short*)(ws + OFF_Z1);
  unsigned short* z2 = (unsigned short*)(ws + OFF_Z2);
  unsigned short* bc = (unsigned short*)(ws + OFF_BC);
  unsigned short* xa = (unsigned short*)(ws + OFF_XA);

  k_pack_x<<<dim3(4 * NPIX / 256), dim3(256), 0, stream>>>(x, xp);

  dim3 cg4(16, 16, 4);
  k_conv16<<<cg4, dim3(256), 0, stream>>>(xp, wtb + W_IN, b_in, z1);
  k_conv64<1, 4, 64, false, 0><<<cg4, dim3(256), 0, stream>>>(
      z1, z1, wtb + W_HID, b_hid, 64, nullptr, z2);
  k_conv64<1, 4, 64, false, 0><<<cg4, dim3(256), 0, stream>>>(
      z2, z2, wtb + W_B1, b_b1, 64, nullptr, z1);
  k_conv64<1, 4, 64, false, 0><<<cg4, dim3(256), 0, stream>>>(
      z2, z2, wtb + W_B21, b_b21, 64, nullptr, bc);
  k_conv64<1, 4, 64, false, 1><<<cg4, dim3(256), 0, stream>>>(
      z2, z2, wtb + W_B22, b_b22, 64, bc, bc);
  k_conv64<2, 1, 16, false, 0><<<cg4, dim3(256), 0, stream>>>(
      z1, bc, wtb + W_O1, b_out, 15, nullptr, xa);

  k_red_ae<<<dim3(NB_RED), dim3(256), 0, stream>>>(x, xa, part);
  k_final<<<dim3(1), dim3(256), 0, stream>>>(part, out);
}